// Round 8
// baseline (1443.217 us; speedup 1.0000x reference)
//
#include <hip/hip_runtime.h>
#include <math.h>

// Problem constants (fixed by the reference)
#define BN 16384
#define DN 512
#define KN 16384
#define HN 256
#define ZN 128
#define CAP 16
#define DELTA 4e-3f

using u16 = unsigned short;
using f16x8 = __attribute__((ext_vector_type(8))) _Float16;
using f32x4 = __attribute__((ext_vector_type(4))) float;

__device__ __forceinline__ u16 hbits(_Float16 h) {
    union { _Float16 h; u16 u; } x; x.h = h; return x.u;
}

// ---------------------------------------------------------------------------
// Encoder: features[B,512] -> Linear -> LN -> GELU -> Linear.
// Writes encoded fp32 (encF, exact-decision input) and the fp16 split
// A2[row][256] = [f16(x) | f16((x - hi)*2048)] (MFMA input).
// ---------------------------------------------------------------------------
__global__ __launch_bounds__(256) void enc_kernel(
    const float* __restrict__ feat, const float* __restrict__ W1, const float* __restrict__ b1,
    const float* __restrict__ g1, const float* __restrict__ be1,
    const float* __restrict__ W2, const float* __restrict__ b2,
    u16* __restrict__ A2, float* __restrict__ encF)
{
    __shared__ float xf[8][512];
    __shared__ float hb[8][256];
    __shared__ float red1[4][8];
    __shared__ float red2[4][8];
    const int tid = threadIdx.x;
    const int rbase = blockIdx.x * 8;

    {
        const float4* src = (const float4*)(feat + rbase * 512);
        float4* dst = (float4*)&xf[0][0];
        #pragma unroll
        for (int i = 0; i < 4; ++i) dst[tid * 4 + i] = src[tid * 4 + i];
    }
    __syncthreads();

    const int j = tid;
    float acc[8];
    {
        float bias = b1[j];
        #pragma unroll
        for (int r = 0; r < 8; ++r) acc[r] = bias;
    }
    for (int k = 0; k < 512; k += 4) {
        float w0 = W1[(k + 0) * 256 + j];
        float w1 = W1[(k + 1) * 256 + j];
        float w2 = W1[(k + 2) * 256 + j];
        float w3 = W1[(k + 3) * 256 + j];
        #pragma unroll
        for (int r = 0; r < 8; ++r) {
            float4 x = *((const float4*)&xf[r][k]);
            acc[r] = fmaf(x.x, w0, acc[r]);
            acc[r] = fmaf(x.y, w1, acc[r]);
            acc[r] = fmaf(x.z, w2, acc[r]);
            acc[r] = fmaf(x.w, w3, acc[r]);
        }
    }

    float s1[8], s2[8];
    #pragma unroll
    for (int r = 0; r < 8; ++r) { s1[r] = acc[r]; s2[r] = acc[r] * acc[r]; }
    #pragma unroll
    for (int m = 1; m < 64; m <<= 1) {
        #pragma unroll
        for (int r = 0; r < 8; ++r) {
            s1[r] += __shfl_xor(s1[r], m, 64);
            s2[r] += __shfl_xor(s2[r], m, 64);
        }
    }
    const int wave = tid >> 6, lane = tid & 63;
    if (lane == 0) {
        #pragma unroll
        for (int r = 0; r < 8; ++r) { red1[wave][r] = s1[r]; red2[wave][r] = s2[r]; }
    }
    __syncthreads();
    {
        float gg = g1[j], bb = be1[j];
        #pragma unroll
        for (int r = 0; r < 8; ++r) {
            float sum = red1[0][r] + red1[1][r] + red1[2][r] + red1[3][r];
            float ssq = red2[0][r] + red2[1][r] + red2[2][r] + red2[3][r];
            float mu = sum * (1.0f / 256.0f);
            float var = fmaxf(ssq * (1.0f / 256.0f) - mu * mu, 0.0f);
            float rstd = rsqrtf(var + 1e-5f);
            float t = (acc[r] - mu) * rstd * gg + bb;
            hb[r][j] = 0.5f * t * (1.0f + erff(t * 0.70710678118654752f));
        }
    }
    __syncthreads();

    const int j2 = tid & 127;
    const int rh = tid >> 7;
    float a2[4];
    {
        float bias2 = b2[j2];
        #pragma unroll
        for (int r = 0; r < 4; ++r) a2[r] = bias2;
    }
    for (int k = 0; k < 256; k += 4) {
        float w0 = W2[(k + 0) * 128 + j2];
        float w1 = W2[(k + 1) * 128 + j2];
        float w2v = W2[(k + 2) * 128 + j2];
        float w3 = W2[(k + 3) * 128 + j2];
        #pragma unroll
        for (int r = 0; r < 4; ++r) {
            float4 h = *((const float4*)&hb[rh * 4 + r][k]);
            a2[r] = fmaf(h.x, w0, a2[r]);
            a2[r] = fmaf(h.y, w1, a2[r]);
            a2[r] = fmaf(h.z, w2v, a2[r]);
            a2[r] = fmaf(h.w, w3, a2[r]);
        }
    }
    #pragma unroll
    for (int r = 0; r < 4; ++r) {
        int row = rbase + rh * 4 + r;
        float v = a2[r];
        encF[row * 128 + j2] = v;
        _Float16 h0 = (_Float16)v;
        _Float16 h1 = (_Float16)((v - (float)h0) * 2048.0f);
        A2[row * 256 + j2]       = hbits(h0);
        A2[row * 256 + 128 + j2] = hbits(h1);
    }
}

// ---------------------------------------------------------------------------
// cbS[k][256] = [f16(c) | f16((c - hi)*2048)]
// ---------------------------------------------------------------------------
__global__ __launch_bounds__(256) void cbsplit_kernel(
    const float* __restrict__ cb, u16* __restrict__ cbS)
{
    const int t = blockIdx.x * 256 + threadIdx.x;   // over 16384*128
    const int k = t >> 7, z = t & 127;
    float v = cb[t];
    _Float16 h0 = (_Float16)v;
    _Float16 h1 = (_Float16)((v - (float)h0) * 2048.0f);
    cbS[k * 256 + z]       = hbits(h0);
    cbS[k * 256 + 128 + z] = hbits(h1);
}

// ---------------------------------------------------------------------------
// cnorm[k] = ||codebook[k]||^2 exact fp32 (one wave per codebook row)
// ---------------------------------------------------------------------------
__global__ __launch_bounds__(256) void cnorm_kernel(
    const float* __restrict__ cb, float* __restrict__ cnorm)
{
    const int tid = threadIdx.x;
    const int wave = tid >> 6, lane = tid & 63;
    const int row = blockIdx.x * 4 + wave;
    const float2 p = *((const float2*)(cb + row * 128 + lane * 2));
    float s = fmaf(p.x, p.x, p.y * p.y);
    #pragma unroll
    for (int m = 1; m < 64; m <<= 1) s += __shfl_xor(s, m, 64);
    if (lane == 0) cnorm[row] = s;
}

// ---------------------------------------------------------------------------
// MFMA distance, candidate generator. Per thread: top-3 of its 128 cols per
// row-slot. Per (row, quarter): block computes approx min; every top-3 entry
// within DELTA of it is dumped (LDS-atomic slots, cap CAP). Final selection
// is exact (recheck_kernel).
// NOTE r7 fix: staging copies 8 x uint4 = 64 u16 per thread (was 4 -> half
// of every z-half was uninitialized LDS; the bug behind rounds 4-7).
// ---------------------------------------------------------------------------
__global__ __launch_bounds__(256) void dist_kernel(
    const u16* __restrict__ A2, const u16* __restrict__ cbS,
    const float* __restrict__ cnorm,
    int* __restrict__ gcand, int* __restrict__ gcnt)
{
    __shared__ u16 cs[128][136];     // 34.8 KB
    __shared__ float qmL[2][2][32];  // [wrow][wcol][rloc]
    __shared__ int cnt[64];

    const int tid = threadIdx.x;
    const int wave = tid >> 6, lane = tid & 63;
    const int wrow = wave >> 1, wcol = wave & 1;
    const int lr = lane & 15, q = lane >> 4;
    const int rt = blockIdx.x >> 2;       // 256 row-tiles
    const int kh = blockIdx.x & 3;        // 4 K-quarters
    const int rbase = rt * 64;
    const int kbase = kh * 4096;

    if (tid < 64) cnt[tid] = 0;

    // persistent A fragments: ab[fr][ks]: ks 0..3 = hi z-steps, 4..7 = lo
    f16x8 ab[2][8];
    #pragma unroll
    for (int fr = 0; fr < 2; ++fr) {
        const u16* ap = A2 + (rbase + wrow * 32 + fr * 16 + lr) * 256 + q * 8;
        #pragma unroll
        for (int ks = 0; ks < 8; ++ks)
            ab[fr][ks] = *((const f16x8*)(ap + ks * 32));
    }

    float m1[8], m2[8], m3[8]; int i1[8], i2[8], i3[8];
    #pragma unroll
    for (int s = 0; s < 8; ++s) {
        m1[s] = 3.4e38f; m2[s] = 3.4e38f; m3[s] = 3.4e38f;
        i1[s] = 0; i2[s] = 0; i3[s] = 0;
    }

    const int scol = tid & 127;      // staging col
    const int sh   = tid >> 7;       // staging half (c0 / c1s)

    for (int kc = 0; kc < 4096; kc += 128) {
        f32x4 accA[2][4], accB[2][4];
        #pragma unroll
        for (int fr = 0; fr < 2; ++fr)
            #pragma unroll
            for (int fc = 0; fc < 4; ++fc) {
                accA[fr][fc] = (f32x4){0.f, 0.f, 0.f, 0.f};
                accB[fr][fc] = (f32x4){0.f, 0.f, 0.f, 0.f};
            }

        #pragma unroll
        for (int zh = 0; zh < 2; ++zh) {
            __syncthreads();
            {   // stage: cs[col][0..63] = c0 z-half, [64..127] = c1s z-half
                // FULL 64 u16 per thread (8 x uint4) — the r7 fix.
                const u16* src = cbS + (kbase + kc + scol) * 256 + sh * 128 + zh * 64;
                u16* d = &cs[scol][sh * 64];
                #pragma unroll
                for (int i = 0; i < 8; ++i)
                    *((uint4*)(d + i * 8)) = *((const uint4*)(src + i * 8));
            }
            __syncthreads();

            const int a0 = zh * 2;       // hi ksteps for this z-half
            const int a1 = 4 + zh * 2;   // lo ksteps
            #pragma unroll
            for (int fc = 0; fc < 4; ++fc) {
                const u16* cp = &cs[wcol * 64 + fc * 16 + lr][0];
                #pragma unroll
                for (int i = 0; i < 2; ++i) {
                    f16x8 b0 = *((const f16x8*)(cp + i * 32 + q * 8));        // c0
                    f16x8 b1 = *((const f16x8*)(cp + 64 + i * 32 + q * 8));   // c1s
                    #pragma unroll
                    for (int fr = 0; fr < 2; ++fr) {
                        accA[fr][fc] = __builtin_amdgcn_mfma_f32_16x16x32_f16(ab[fr][a0 + i], b0, accA[fr][fc], 0, 0, 0);
                        accB[fr][fc] = __builtin_amdgcn_mfma_f32_16x16x32_f16(ab[fr][a0 + i], b1, accB[fr][fc], 0, 0, 0);
                        accB[fr][fc] = __builtin_amdgcn_mfma_f32_16x16x32_f16(ab[fr][a1 + i], b0, accB[fr][fc], 0, 0, 0);
                    }
                }
            }
        }

        // epilogue: score = cn - 2*(A + B/2048); per-thread top-3 per slot
        #pragma unroll
        for (int fc = 0; fc < 4; ++fc) {
            int col = kbase + kc + wcol * 64 + fc * 16 + lr;
            float cn = cnorm[col];
            #pragma unroll
            for (int fr = 0; fr < 2; ++fr)
                #pragma unroll
                for (int r = 0; r < 4; ++r) {
                    float dot = fmaf(accB[fr][fc][r], 4.8828125e-4f, accA[fr][fc][r]);
                    float v = fmaf(-2.0f, dot, cn);
                    int s = fr * 4 + r;
                    if (v < m3[s]) {
                        if (v < m1[s]) {
                            m3[s] = m2[s]; i3[s] = i2[s];
                            m2[s] = m1[s]; i2[s] = i1[s];
                            m1[s] = v;     i1[s] = col;
                        } else if (v < m2[s]) {
                            m3[s] = m2[s]; i3[s] = i2[s];
                            m2[s] = v;     i2[s] = col;
                        } else {
                            m3[s] = v;     i3[s] = col;
                        }
                    }
                }
        }
    }

    // per-slot min over the 16 lr lanes
    #pragma unroll
    for (int s = 0; s < 8; ++s) {
        float b = m1[s];
        #pragma unroll
        for (int mask = 1; mask < 16; mask <<= 1)
            b = fminf(b, __shfl_xor(b, mask, 64));
        if (lr == 0) qmL[wrow][wcol][(s >> 2) * 16 + q * 4 + (s & 3)] = b;
    }
    __syncthreads();

    // dump: any of this thread's top-3 within DELTA of the quarter-row min
    #pragma unroll
    for (int s = 0; s < 8; ++s) {
        int rloc = (s >> 2) * 16 + q * 4 + (s & 3);
        int row_local = wrow * 32 + rloc;
        float thr = fminf(qmL[wrow][0][rloc], qmL[wrow][1][rloc]) + DELTA;
        int gbase = (kh * 16384 + rbase + row_local) * CAP;
        if (m1[s] <= thr) { int p = atomicAdd(&cnt[row_local], 1); if (p < CAP) gcand[gbase + p] = i1[s]; }
        if (m2[s] <= thr) { int p = atomicAdd(&cnt[row_local], 1); if (p < CAP) gcand[gbase + p] = i2[s]; }
        if (m3[s] <= thr) { int p = atomicAdd(&cnt[row_local], 1); if (p < CAP) gcand[gbase + p] = i3[s]; }
    }
    __syncthreads();
    if (tid < 64) gcnt[kh * 16384 + rbase + tid] = min(cnt[tid], CAP);
}

// ---------------------------------------------------------------------------
// Exact decision: one wave per row; evaluate ALL dumped candidates with the
// round-3-proven formula (sequential-z fmaf on fp32 encoded, score =
// fmaf(-2, dot, cnorm)); full 64-lane argmin with index tie-break.
// ---------------------------------------------------------------------------
__global__ __launch_bounds__(256) void recheck_kernel(
    const float* __restrict__ encF, const float* __restrict__ cb,
    const float* __restrict__ cnorm,
    const int* __restrict__ gcand, const int* __restrict__ gcnt,
    int* __restrict__ idx_ws)
{
    const int tid = threadIdx.x;
    const int wave = tid >> 6, lane = tid & 63;
    const int row = blockIdx.x * 4 + wave;

    int c0 = gcnt[row];
    int c1 = gcnt[16384 + row];
    int c2 = gcnt[2 * 16384 + row];
    int c3 = gcnt[3 * 16384 + row];
    int M = c0 + c1 + c2 + c3;   // in [4, 64]

    int ci = 0x7FFFFFFF;
    float v = 3.4e38f;
    if (lane < M) {
        int l = lane, qq = 0;
        if (l >= c0) { l -= c0; qq = 1;
            if (l >= c1) { l -= c1; qq = 2;
                if (l >= c2) { l -= c2; qq = 3; } } }
        ci = gcand[(qq * 16384 + row) * CAP + l];
        ci = min(max(ci, 0), KN - 1);

        const float* x = encF + row * 128;
        const float* c = cb + ci * 128;
        float acc = 0.0f;
        #pragma unroll 8
        for (int z = 0; z < 128; z += 4) {
            float4 xv = *((const float4*)(x + z));
            float4 cv = *((const float4*)(c + z));
            acc = fmaf(xv.x, cv.x, acc);
            acc = fmaf(xv.y, cv.y, acc);
            acc = fmaf(xv.z, cv.z, acc);
            acc = fmaf(xv.w, cv.w, acc);
        }
        v = fmaf(-2.0f, acc, cnorm[ci]);
    }

    #pragma unroll
    for (int m = 1; m < 64; m <<= 1) {
        float ov = __shfl_xor(v, m, 64);
        int   oi = __shfl_xor(ci, m, 64);
        if (ov < v || (ov == v && oi < ci)) { v = ov; ci = oi; }
    }
    if (lane == 0) idx_ws[row] = ci;
}

// ---------------------------------------------------------------------------
// Decoder: gather codebook row, Linear->LN->GELU->Linear, per-row MSE + sum.
// ---------------------------------------------------------------------------
__global__ __launch_bounds__(256) void dec_kernel(
    const float* __restrict__ feat, const float* __restrict__ cb,
    const float* __restrict__ W3, const float* __restrict__ b3,
    const float* __restrict__ g2, const float* __restrict__ be2,
    const float* __restrict__ W4, const float* __restrict__ b4,
    const int* __restrict__ idx_ws,
    float* __restrict__ re_ws, float* __restrict__ sum_ws)
{
    __shared__ float qb[8][128];
    __shared__ float dh[8][256];
    __shared__ float red1[4][8];
    __shared__ float red2[4][8];
    __shared__ int idxs[8];
    const int tid = threadIdx.x;
    const int rbase = blockIdx.x * 8;

    if (tid < 8) {
        int sel = idx_ws[rbase + tid];
        idxs[tid] = min(max(sel, 0), KN - 1);
    }
    __syncthreads();
    {
        int r = tid >> 5, i = (tid & 31) * 4;
        *((float4*)&qb[r][i]) = *((const float4*)(cb + idxs[r] * 128 + i));
    }
    __syncthreads();

    const int j = tid;
    float acc[8];
    {
        float bias = b3[j];
        #pragma unroll
        for (int r = 0; r < 8; ++r) acc[r] = bias;
    }
    for (int k = 0; k < 128; k += 4) {
        float w0 = W3[(k + 0) * 256 + j];
        float w1 = W3[(k + 1) * 256 + j];
        float w2 = W3[(k + 2) * 256 + j];
        float w3v = W3[(k + 3) * 256 + j];
        #pragma unroll
        for (int r = 0; r < 8; ++r) {
            float4 qv = *((const float4*)&qb[r][k]);
            acc[r] = fmaf(qv.x, w0, acc[r]);
            acc[r] = fmaf(qv.y, w1, acc[r]);
            acc[r] = fmaf(qv.z, w2, acc[r]);
            acc[r] = fmaf(qv.w, w3v, acc[r]);
        }
    }

    float s1[8], s2[8];
    #pragma unroll
    for (int r = 0; r < 8; ++r) { s1[r] = acc[r]; s2[r] = acc[r] * acc[r]; }
    #pragma unroll
    for (int m = 1; m < 64; m <<= 1) {
        #pragma unroll
        for (int r = 0; r < 8; ++r) {
            s1[r] += __shfl_xor(s1[r], m, 64);
            s2[r] += __shfl_xor(s2[r], m, 64);
        }
    }
    const int wave = tid >> 6, lane = tid & 63;
    if (lane == 0) {
        #pragma unroll
        for (int r = 0; r < 8; ++r) { red1[wave][r] = s1[r]; red2[wave][r] = s2[r]; }
    }
    __syncthreads();
    {
        float gg = g2[j], bb = be2[j];
        #pragma unroll
        for (int r = 0; r < 8; ++r) {
            float sum = red1[0][r] + red1[1][r] + red1[2][r] + red1[3][r];
            float ssq = red2[0][r] + red2[1][r] + red2[2][r] + red2[3][r];
            float mu = sum * (1.0f / 256.0f);
            float var = fmaxf(ssq * (1.0f / 256.0f) - mu * mu, 0.0f);
            float rstd = rsqrtf(var + 1e-5f);
            float t = (acc[r] - mu) * rstd * gg + bb;
            dh[r][j] = 0.5f * t * (1.0f + erff(t * 0.70710678118654752f));
        }
    }
    __syncthreads();

    float a0[8], a1[8];
    {
        float bias0 = b4[tid], bias1 = b4[tid + 256];
        #pragma unroll
        for (int r = 0; r < 8; ++r) { a0[r] = bias0; a1[r] = bias1; }
    }
    for (int k = 0; k < 256; k += 4) {
        float w00 = W4[(k + 0) * 512 + tid];
        float w01 = W4[(k + 0) * 512 + tid + 256];
        float w10 = W4[(k + 1) * 512 + tid];
        float w11 = W4[(k + 1) * 512 + tid + 256];
        float w20 = W4[(k + 2) * 512 + tid];
        float w21 = W4[(k + 2) * 512 + tid + 256];
        float w30 = W4[(k + 3) * 512 + tid];
        float w31 = W4[(k + 3) * 512 + tid + 256];
        #pragma unroll
        for (int r = 0; r < 8; ++r) {
            float4 h = *((const float4*)&dh[r][k]);
            a0[r] = fmaf(h.x, w00, a0[r]); a1[r] = fmaf(h.x, w01, a1[r]);
            a0[r] = fmaf(h.y, w10, a0[r]); a1[r] = fmaf(h.y, w11, a1[r]);
            a0[r] = fmaf(h.z, w20, a0[r]); a1[r] = fmaf(h.z, w21, a1[r]);
            a0[r] = fmaf(h.w, w30, a0[r]); a1[r] = fmaf(h.w, w31, a1[r]);
        }
    }
    float e[8];
    #pragma unroll
    for (int r = 0; r < 8; ++r) {
        float f0 = feat[(rbase + r) * 512 + tid];
        float f1 = feat[(rbase + r) * 512 + tid + 256];
        float d0 = a0[r] - f0, d1 = a1[r] - f1;
        e[r] = d0 * d0 + d1 * d1;
    }
    #pragma unroll
    for (int m = 1; m < 64; m <<= 1) {
        #pragma unroll
        for (int r = 0; r < 8; ++r) e[r] += __shfl_xor(e[r], m, 64);
    }
    if (lane == 0) {
        #pragma unroll
        for (int r = 0; r < 8; ++r) red1[wave][r] = e[r];
    }
    __syncthreads();
    if (tid < 8) {
        float s = (red1[0][tid] + red1[1][tid] + red1[2][tid] + red1[3][tid]) * (1.0f / 512.0f);
        re_ws[rbase + tid] = s;
        atomicAdd(sum_ws, s);
    }
}

// ---------------------------------------------------------------------------
// Finalize: scale = mean(re)+1e-8; MDL bits; write all 4 fp32 outputs.
// ---------------------------------------------------------------------------
__global__ __launch_bounds__(256) void fin_kernel(
    const float* __restrict__ re_ws, const float* __restrict__ sum_ws,
    const int* __restrict__ idx_ws, float* __restrict__ out)
{
    const int i = blockIdx.x * 256 + threadIdx.x;
    const float scale = (*sum_ws) * (1.0f / 16384.0f) + 1e-8f;
    const float re = re_ws[i];
    const float lp = -fabsf(re) / scale - logf(2.0f * scale);
    const float eb = -lp * 1.4426950408889634f;
    const float tb = 14.0f + eb;
    const float ratio = 16384.0f / tb;
    out[i]             = re;
    out[16384 + i]     = ratio;
    out[2 * 16384 + i] = tb;
    out[3 * 16384 + i] = (float)idx_ws[i];
}

// ---------------------------------------------------------------------------
extern "C" void kernel_launch(void* const* d_in, const int* in_sizes, int n_in,
                              void* d_out, int out_size, void* d_ws, size_t ws_size,
                              hipStream_t stream)
{
    const float* feat = (const float*)d_in[0];
    const float* W1   = (const float*)d_in[1];
    const float* b1   = (const float*)d_in[2];
    const float* g1   = (const float*)d_in[3];
    const float* be1  = (const float*)d_in[4];
    const float* W2   = (const float*)d_in[5];
    const float* b2   = (const float*)d_in[6];
    const float* cb   = (const float*)d_in[7];
    const float* W3   = (const float*)d_in[8];
    const float* b3   = (const float*)d_in[9];
    const float* g2   = (const float*)d_in[10];
    const float* be2  = (const float*)d_in[11];
    const float* W4   = (const float*)d_in[12];
    const float* b4   = (const float*)d_in[13];

    char* ws = (char*)d_ws;
    u16*   A2   = (u16*)ws;                                   // 8 MB
    u16*   cbS  = (u16*)(ws + ((size_t)8 << 20));             // 8 MB
    float* encF = (float*)(ws + ((size_t)16 << 20));          // 8 MB
    char*  base = ws + ((size_t)24 << 20);
    float* cnorm  = (float*)(base);                           // 64 KB
    int*   gcand  = (int*)  (base + ((size_t)64   << 10));    // 4 MB  [quarter][row][CAP]
    int*   gcnt   = (int*)  (base + ((size_t)4160 << 10));    // 256 KB [quarter][row]
    float* re_ws  = (float*)(base + ((size_t)4416 << 10));    // 64 KB
    int*   idx_ws = (int*)  (base + ((size_t)4480 << 10));    // 64 KB
    float* sum_ws = (float*)(base + ((size_t)4544 << 10));    // 4 B

    hipMemsetAsync(sum_ws, 0, sizeof(float), stream);

    hipLaunchKernelGGL(enc_kernel,     dim3(BN / 8), dim3(256), 0, stream,
                       feat, W1, b1, g1, be1, W2, b2, A2, encF);
    hipLaunchKernelGGL(cbsplit_kernel, dim3(KN * ZN / 256), dim3(256), 0, stream, cb, cbS);
    hipLaunchKernelGGL(cnorm_kernel,   dim3(KN / 4), dim3(256), 0, stream, cb, cnorm);
    hipLaunchKernelGGL(dist_kernel,    dim3((BN / 64) * 4), dim3(256), 0, stream,
                       A2, cbS, cnorm, gcand, gcnt);
    hipLaunchKernelGGL(recheck_kernel, dim3(BN / 4), dim3(256), 0, stream,
                       encF, cb, cnorm, gcand, gcnt, idx_ws);
    hipLaunchKernelGGL(dec_kernel,     dim3(BN / 8), dim3(256), 0, stream,
                       feat, cb, W3, b3, g2, be2, W4, b4, idx_ws, re_ws, sum_ws);
    hipLaunchKernelGGL(fin_kernel,     dim3(BN / 256), dim3(256), 0, stream,
                       re_ws, sum_ws, idx_ws, (float*)d_out);
}